// Round 5
// baseline (277.031 us; speedup 1.0000x reference)
//
#include <hip/hip_runtime.h>

// PolyAttention on MI355X (gfx950).
// cvt f32->bf16 -> fused QKV GEMM (256x256, BK=64, K-split half-tile 8-phase
// pipeline, counted vmcnt, swizzled LDS, rope fused, V transposed)
// -> causal poly(^4) attention -> output GEMM.  b=2, n=2048, d=2048, h=16, hd=128.

typedef __bf16 bf16;
typedef __bf16 bf16x8 __attribute__((ext_vector_type(8)));
typedef __bf16 bf16x4 __attribute__((ext_vector_type(4)));
typedef float f32x4 __attribute__((ext_vector_type(4)));

#define GLD(g, l)                                                   \
  __builtin_amdgcn_global_load_lds(                                 \
      (const __attribute__((address_space(1))) void*)(g),           \
      (__attribute__((address_space(3))) void*)(l), 16, 0, 0)

#define MFMA(a, b, c) __builtin_amdgcn_mfma_f32_16x16x32_bf16(a, b, c, 0, 0, 0)

// ---------- f32 -> bf16 conversion, 4 elems/thread ----------
__global__ __launch_bounds__(256) void k_cvt(const float* __restrict__ in,
                                             bf16* __restrict__ out, int n4) {
  int i = blockIdx.x * 256 + threadIdx.x;
  if (i >= n4) return;
  float4 v = reinterpret_cast<const float4*>(in)[i];
  bf16x4 o = {(bf16)v.x, (bf16)v.y, (bf16)v.z, (bf16)v.w};
  reinterpret_cast<bf16x4*>(out)[i] = o;
}

// ---------- 3x weight cvt into concatenated wqkv (6144 x 2048) ----------
__global__ __launch_bounds__(256) void k_cvt3(const float* __restrict__ a,
                                              const float* __restrict__ b,
                                              const float* __restrict__ c,
                                              bf16* __restrict__ out) {
  int i = blockIdx.x * 256 + threadIdx.x;
  const float* src = (i < 1048576) ? a : ((i < 2097152) ? b : c);
  int off = i & 1048575;
  float4 v = reinterpret_cast<const float4*>(src)[off];
  bf16x4 o = {(bf16)v.x, (bf16)v.y, (bf16)v.z, (bf16)v.w};
  reinterpret_cast<bf16x4*>(out)[i] = o;
}

// ---------- RoPE cos/sin table: (n=2048, half=64) ----------
__global__ __launch_bounds__(256) void k_rope_tab(float* __restrict__ ct,
                                                  float* __restrict__ st) {
  int i = blockIdx.x * 256 + threadIdx.x;
  if (i >= 2048 * 64) return;
  int pos = i >> 6, f = i & 63;
  float theta = exp2f(-(float)f * 0.20762050593046014f);  // 10000^(-f/64)
  float ang = (float)pos * theta;
  ct[i] = cosf(ang);
  st[i] = sinf(ang);
}

// ---------- fused QKV GEMM, 256x256 tile, K-split 8-phase pipeline ----------
// C = A*B^T, A: 4096x2048 (xb), B: 6144x2048 (wqkv). 8 waves (2M x 4N),
// per-wave 128x64 (8x4 frags). LDS: 2 bufs x {A-k0,A-k1,B-k0,B-k1} x 16KB.
// K-half layout: [128 LDS-rows of 128B], LDS-row j = tile rows {2j,2j+1},
// chunk swizzle cl -> cl ^ (j&7) (proven zero-conflict). Stage = linear dest
// + inverse-swizzled global source. Gates: vmcnt(4) at ph2/ph4 end only.
__global__ __launch_bounds__(512, 2) void k_gemm_qkv(
    const bf16* __restrict__ Am, const bf16* __restrict__ Bm,
    bf16* __restrict__ Qp, bf16* __restrict__ Kp, bf16* __restrict__ Vt,
    const float* __restrict__ ct, const float* __restrict__ st) {
  __shared__ __align__(16) char LDS[131072];
  const int tid = threadIdx.x, l = tid & 63, w = tid >> 6;
  const int lr = l & 15, g = l >> 4;
  const int wm = w >> 2, wn = w & 3;
  // XCD swizzle: 384 blocks, XCD k owns logical tiles [k*48, k*48+47]
  const int bid = blockIdx.x;
  const int swz = (bid & 7) * 48 + (bid >> 3);
  const int tn = (swz % 24) * 256;
  const int tm = (swz / 24) * 256;

  // stage constants: thread -> (row, kcol) with inverse swizzle
  const int clv = (tid & 7) ^ ((tid >> 3) & 7);
  const int srow0 = 2 * (tid >> 3) + (clv >> 2);
  const int skcol = (clv & 3) * 8;
  const bf16* As0 = Am + (size_t)(tm + srow0) * 2048 + skcol;
  const bf16* As1 = Am + (size_t)(tm + 128 + srow0) * 2048 + skcol;
  const bf16* Bs0 = Bm + (size_t)(tn + srow0) * 2048 + skcol;
  const bf16* Bs1 = Bm + (size_t)(tn + 128 + srow0) * 2048 + skcol;

  // ds_read per-lane offsets (bytes): row parity + g chunk, XOR j&7
  const int cp = (((lr & 1) << 2) | g) ^ ((lr >> 1) & 7);
  const int aoff = wm * 8192 + (lr >> 1) * 128 + cp * 16;
  const int boff = wn * 4096 + (lr >> 1) * 128 + cp * 16;

#define STAGE(slotoff, p0, p1, kk)                       \
  {                                                      \
    GLD((p0) + (kk), LDS + (slotoff) + tid * 16);        \
    GLD((p1) + (kk), LDS + (slotoff) + 8192 + tid * 16); \
  }

  f32x4 acc[8][4] = {};

  // prologue: tile 0's four K-half slots into buf0
  STAGE(0, As0, As1, 0);          // A-k0(0)
  STAGE(32768, Bs0, Bs1, 0);      // B-k0(0)
  STAGE(16384, As0, As1, 32);     // A-k1(0)
  STAGE(49152, Bs0, Bs1, 32);     // B-k1(0)
  asm volatile("s_waitcnt vmcnt(4)" ::: "memory");
  __builtin_amdgcn_s_barrier();
  asm volatile("" ::: "memory");

  for (int t = 0; t < 32; ++t) {
    const int c = t & 1, o = c * 65536, on = (c ^ 1) * 65536;
    const int kn = (t + 1) * 64;
    const bool lastT = (t == 31);
    const char* pa0 = LDS + o;
    const char* pa1 = LDS + o + 16384;
    const char* pb0 = LDS + o + 32768;
    const char* pb1 = LDS + o + 49152;
    bf16x8 a[8], b0, b1;

    // ---- ph1: kh0, nf{0,1} ----
#pragma unroll
    for (int fm = 0; fm < 8; ++fm)
      a[fm] = *reinterpret_cast<const bf16x8*>(pa0 + aoff + fm * 1024);
    b0 = *reinterpret_cast<const bf16x8*>(pb0 + boff);
    b1 = *reinterpret_cast<const bf16x8*>(pb0 + boff + 1024);
    if (!lastT) STAGE(on, As0, As1, kn);
    __builtin_amdgcn_s_setprio(1);
#pragma unroll
    for (int fm = 0; fm < 8; ++fm) {
      acc[fm][0] = MFMA(a[fm], b0, acc[fm][0]);
      acc[fm][1] = MFMA(a[fm], b1, acc[fm][1]);
    }
    __builtin_amdgcn_s_setprio(0);
    __builtin_amdgcn_s_barrier();
    asm volatile("" ::: "memory");

    // ---- ph2: kh0, nf{2,3} ----
    b0 = *reinterpret_cast<const bf16x8*>(pb0 + boff + 2048);
    b1 = *reinterpret_cast<const bf16x8*>(pb0 + boff + 3072);
    if (!lastT) STAGE(on + 32768, Bs0, Bs1, kn);
    __builtin_amdgcn_s_setprio(1);
#pragma unroll
    for (int fm = 0; fm < 8; ++fm) {
      acc[fm][2] = MFMA(a[fm], b0, acc[fm][2]);
      acc[fm][3] = MFMA(a[fm], b1, acc[fm][3]);
    }
    __builtin_amdgcn_s_setprio(0);
    if (lastT)
      asm volatile("s_waitcnt vmcnt(0)" ::: "memory");
    else
      asm volatile("s_waitcnt vmcnt(4)" ::: "memory");
    __builtin_amdgcn_s_barrier();
    asm volatile("" ::: "memory");

    // ---- ph3: kh1, nf{0,1} ----
#pragma unroll
    for (int fm = 0; fm < 8; ++fm)
      a[fm] = *reinterpret_cast<const bf16x8*>(pa1 + aoff + fm * 1024);
    b0 = *reinterpret_cast<const bf16x8*>(pb1 + boff);
    b1 = *reinterpret_cast<const bf16x8*>(pb1 + boff + 1024);
    if (!lastT) STAGE(on + 16384, As0, As1, kn + 32);
    __builtin_amdgcn_s_setprio(1);
#pragma unroll
    for (int fm = 0; fm < 8; ++fm) {
      acc[fm][0] = MFMA(a[fm], b0, acc[fm][0]);
      acc[fm][1] = MFMA(a[fm], b1, acc[fm][1]);
    }
    __builtin_amdgcn_s_setprio(0);
    __builtin_amdgcn_s_barrier();
    asm volatile("" ::: "memory");

    // ---- ph4: kh1, nf{2,3} ----
    b0 = *reinterpret_cast<const bf16x8*>(pb1 + boff + 2048);
    b1 = *reinterpret_cast<const bf16x8*>(pb1 + boff + 3072);
    if (!lastT) STAGE(on + 49152, Bs0, Bs1, kn + 32);
    __builtin_amdgcn_s_setprio(1);
#pragma unroll
    for (int fm = 0; fm < 8; ++fm) {
      acc[fm][2] = MFMA(a[fm], b0, acc[fm][2]);
      acc[fm][3] = MFMA(a[fm], b1, acc[fm][3]);
    }
    __builtin_amdgcn_s_setprio(0);
    if (!lastT) asm volatile("s_waitcnt vmcnt(4)" ::: "memory");
    __builtin_amdgcn_s_barrier();
    asm volatile("" ::: "memory");
  }

  // ---- epilogue ----
  if (tn < 4096) {
    // Q or K: LDS exchange (2 passes of 128 rows) + rope + store (b,h,n,128)
    bf16* dst = (tn < 2048) ? Qp : Kp;
    const int nb = tn & 2047;
    bf16* E = (bf16*)LDS;  // [128][264]
    for (int pass = 0; pass < 2; ++pass) {
      __syncthreads();
      if (wm == pass) {
#pragma unroll
        for (int fm = 0; fm < 8; ++fm)
#pragma unroll
          for (int nf = 0; nf < 4; ++nf)
#pragma unroll
            for (int rr = 0; rr < 4; ++rr)
              E[(fm * 16 + g * 4 + rr) * 264 + wn * 64 + nf * 16 + lr] =
                  (bf16)acc[fm][nf][rr];
      }
      __syncthreads();
#pragma unroll
      for (int it = 0; it < 8; ++it) {
        int task = it * 512 + tid;  // 128 rows x 2 heads x 16 d4-groups
        int row = task >> 5, rem = task & 31;
        int hd = rem >> 4, dg = (rem & 15) << 2;
        int token = tm + pass * 128 + row;
        int nn = token & 2047, bb = token >> 11;
        f32x4 c4 = *reinterpret_cast<const f32x4*>(ct + nn * 64 + dg);
        f32x4 s4 = *reinterpret_cast<const f32x4*>(st + nn * 64 + dg);
        bf16x4 x1 = *reinterpret_cast<const bf16x4*>(E + row * 264 + hd * 128 + dg);
        bf16x4 x2 = *reinterpret_cast<const bf16x4*>(E + row * 264 + hd * 128 + 64 + dg);
        bf16x4 o1, o2;
#pragma unroll
        for (int j = 0; j < 4; ++j) {
          float a1 = (float)x1[j], a2 = (float)x2[j];
          o1[j] = (bf16)(a1 * c4[j] - a2 * s4[j]);
          o2[j] = (bf16)(a1 * s4[j] + a2 * c4[j]);
        }
        int h_ = (nb >> 7) + hd;
        size_t rb = (((size_t)bb * 16 + h_) * 2048 + nn) * 128;
        *reinterpret_cast<bf16x4*>(dst + rb + dg) = o1;
        *reinterpret_cast<bf16x4*>(dst + rb + 64 + dg) = o2;
      }
    }
  } else {
    // V: transposed store (b,h,128,n), 4 consecutive tokens per bf16x4
#pragma unroll
    for (int fm = 0; fm < 8; ++fm)
#pragma unroll
      for (int nf = 0; nf < 4; ++nf) {
        int row0 = tm + wm * 128 + fm * 16 + g * 4;
        int col = (tn - 4096) + wn * 64 + nf * 16 + lr;
        int bb = row0 >> 11, nn = row0 & 2047;
        int hh = col >> 7, dd = col & 127;
        bf16x4 o = {(bf16)acc[fm][nf][0], (bf16)acc[fm][nf][1],
                    (bf16)acc[fm][nf][2], (bf16)acc[fm][nf][3]};
        *reinterpret_cast<bf16x4*>(
            Vt + (((size_t)bb * 16 + hh) * 128 + dd) * 2048 + nn) = o;
      }
  }
}

// ---------- output GEMM: C(f32) = A * B^T, 4096x2048x2048 (round-4, kept) ----------
__global__ __launch_bounds__(256, 3) void k_gemm_out(const bf16* __restrict__ Am,
                                                     const bf16* __restrict__ Bm,
                                                     float* __restrict__ C) {
  __shared__ __align__(16) char LDS[49152];  // 3 x (8KB A + 8KB B)
  const int tid = threadIdx.x, w = tid >> 6, l = tid & 63;
  const int lr = l & 15, g = l >> 4;
  const int wr = w >> 1, wc = w & 1;
  const int tm = blockIdx.y * 128, tn = blockIdx.x * 128;

  const int rl = tid >> 2;
  const int scol = (((tid & 3) ^ (rl & 3) ^ ((rl >> 2) & 3)) << 3);
  const int xo = ((g ^ (lr & 3) ^ ((lr >> 2) & 3)) << 4);

#define STAGEO(buf, kt)                                                      \
  {                                                                          \
    _Pragma("unroll") for (int i = 0; i < 2; ++i)                            \
        GLD(Am + (size_t)(tm + i * 64 + rl) * 2048 + (kt) + scol,            \
            LDS + (buf) * 16384 + i * 4096 + tid * 16);                      \
    _Pragma("unroll") for (int i = 0; i < 2; ++i)                            \
        GLD(Bm + (size_t)(tn + i * 64 + rl) * 2048 + (kt) + scol,            \
            LDS + (buf) * 16384 + 8192 + i * 4096 + tid * 16);               \
  }

  f32x4 acc[4][4] = {};

  STAGEO(0, 0);
  STAGEO(1, 32);
  int cur = 0, st3 = 2;
  for (int t = 0; t < 63; ++t) {
    asm volatile("s_waitcnt vmcnt(4)" ::: "memory");
    __builtin_amdgcn_s_barrier();
    asm volatile("" ::: "memory");
    if (t < 62) STAGEO(st3, (t + 2) * 32);
    const char* pa = LDS + cur * 16384;
    const char* pb = pa + 8192;
    bf16x8 a[4], b[4];
#pragma unroll
    for (int fm = 0; fm < 4; ++fm)
      a[fm] = *reinterpret_cast<const bf16x8*>(pa + (wr * 64 + fm * 16 + lr) * 64 + xo);
#pragma unroll
    for (int nf = 0; nf < 4; ++nf)
      b[nf] = *reinterpret_cast<const bf16x8*>(pb + (wc * 64 + nf * 16 + lr) * 64 + xo);
    __builtin_amdgcn_s_setprio(1);
#pragma unroll
    for (int fm = 0; fm < 4; ++fm)
#pragma unroll
      for (int nf = 0; nf < 4; ++nf)
        acc[fm][nf] = MFMA(a[fm], b[nf], acc[fm][nf]);
    __builtin_amdgcn_s_setprio(0);
    cur = (cur == 2) ? 0 : cur + 1;
    st3 = (st3 == 2) ? 0 : st3 + 1;
  }
  {
    asm volatile("s_waitcnt vmcnt(0)" ::: "memory");
    __builtin_amdgcn_s_barrier();
    asm volatile("" ::: "memory");
    const char* pa = LDS + cur * 16384;
    const char* pb = pa + 8192;
    bf16x8 a[4], b[4];
#pragma unroll
    for (int fm = 0; fm < 4; ++fm)
      a[fm] = *reinterpret_cast<const bf16x8*>(pa + (wr * 64 + fm * 16 + lr) * 64 + xo);
#pragma unroll
    for (int nf = 0; nf < 4; ++nf)
      b[nf] = *reinterpret_cast<const bf16x8*>(pb + (wc * 64 + nf * 16 + lr) * 64 + xo);
#pragma unroll
    for (int fm = 0; fm < 4; ++fm)
#pragma unroll
      for (int nf = 0; nf < 4; ++nf)
        acc[fm][nf] = MFMA(a[fm], b[nf], acc[fm][nf]);
  }

#pragma unroll
  for (int fm = 0; fm < 4; ++fm)
#pragma unroll
    for (int nf = 0; nf < 4; ++nf)
#pragma unroll
      for (int rr = 0; rr < 4; ++rr) {
        int row = tm + wr * 64 + fm * 16 + g * 4 + rr;
        int col = tn + wc * 64 + nf * 16 + lr;
        C[(size_t)row * 2048 + col] = acc[fm][nf][rr];
      }
}

// ---------- causal poly^4 attention (unchanged) ----------
__global__ __launch_bounds__(256) void k_attn(const bf16* __restrict__ Q,
                                              const bf16* __restrict__ K,
                                              const bf16* __restrict__ Vt,
                                              bf16* __restrict__ O) {
  __shared__ __align__(16) bf16 Ks[128 * 128];
  __shared__ __align__(16) bf16 Vs[128 * 128];  // [hd][kv]
  __shared__ __align__(16) bf16 Ps[64 * 128];
  const int tid = threadIdx.x, w = tid >> 6, l = tid & 63;
  const int lr = l & 15, g = l >> 4;
  const int flat = blockIdx.x;
  const int pair = flat >> 5, bh = flat & 31;
  const size_t base = (size_t)bh * 2048 * 128;
  const int b_ = bh >> 4, h_ = bh & 15;

  for (int seg = 0; seg < 2; ++seg) {
    const int qt = seg ? (31 - pair) : pair;
    const int qbase = qt * 64;
    bf16x8 qf[4];
#pragma unroll
    for (int kc = 0; kc < 4; ++kc)
      qf[kc] = *reinterpret_cast<const bf16x8*>(
          Q + base + (size_t)(qbase + w * 16 + lr) * 128 + kc * 32 + g * 8);

    f32x4 on[8] = {};
    float dn[4] = {};
    const int nt = (qbase >> 7) + 1;

    for (int t = 0; t < nt; ++t) {
      const bf16* kg = K + base + (size_t)t * 128 * 128;
      const bf16* vg = Vt + base + t * 128;
#pragma unroll
      for (int r = 0; r < 8; ++r) {
        int e = r * 2048 + w * 512 + l * 8;
        int row = e >> 7, c = (e >> 3) & 15;
        int sc = ((c ^ (row & 7)) << 3);
        GLD(kg + (row << 7) + sc, Ks + r * 2048 + w * 512);
        GLD(vg + (size_t)row * 2048 + sc, Vs + r * 2048 + w * 512);
      }
      __syncthreads();

      f32x4 s[8] = {};
      __builtin_amdgcn_s_setprio(1);
#pragma unroll
      for (int kc = 0; kc < 4; ++kc)
#pragma unroll
        for (int ni = 0; ni < 8; ++ni) {
          bf16x8 kb = *reinterpret_cast<const bf16x8*>(
              Ks + ((ni * 16 + lr) << 7) + (((kc * 4 + g) ^ (lr & 7)) << 3));
          s[ni] = MFMA(qf[kc], kb, s[ni]);
        }
      __builtin_amdgcn_s_setprio(0);

      float part[4] = {};
#pragma unroll
      for (int ni = 0; ni < 8; ++ni)
#pragma unroll
        for (int r = 0; r < 4; ++r) {
          int lrow = g * 4 + r;
          int qrow = qbase + w * 16 + lrow;
          int col = t * 128 + ni * 16 + lr;
          float v = s[ni][r];
          v = (col <= qrow) ? v : 0.f;
          float v2 = v * v, v4 = v2 * v2;
          part[r] += v4;
          int chunk = ni * 2 + (lr >> 3);
          Ps[((w * 16 + lrow) << 7) + ((chunk ^ (lrow & 7)) << 3) + (lr & 7)] =
              (bf16)v4;
        }
#pragma unroll
      for (int m = 1; m < 16; m <<= 1)
#pragma unroll
        for (int r = 0; r < 4; ++r) part[r] += __shfl_xor(part[r], m, 64);
#pragma unroll
      for (int r = 0; r < 4; ++r) dn[r] += part[r];

      __builtin_amdgcn_s_setprio(1);
#pragma unroll
      for (int kc = 0; kc < 4; ++kc) {
        bf16x8 pa = *reinterpret_cast<const bf16x8*>(
            Ps + ((w * 16 + lr) << 7) + (((kc * 4 + g) ^ (lr & 7)) << 3));
#pragma unroll
        for (int ni = 0; ni < 8; ++ni) {
          bf16x8 vb = *reinterpret_cast<const bf16x8*>(
              Vs + ((ni * 16 + lr) << 7) + (((kc * 4 + g) ^ (lr & 7)) << 3));
          on[ni] = MFMA(pa, vb, on[ni]);
        }
      }
      __builtin_amdgcn_s_setprio(0);
      __syncthreads();
    }

#pragma unroll
    for (int r = 0; r < 4; ++r) {
      float inv = 1.0f / fmaxf(dn[r], 1e-6f);
      int row = qbase + w * 16 + g * 4 + r;
#pragma unroll
      for (int ni = 0; ni < 8; ++ni)
        O[((size_t)b_ * 2048 + row) * 2048 + h_ * 128 + ni * 16 + lr] =
            (bf16)(on[ni][r] * inv);
    }
  }
}

extern "C" void kernel_launch(void* const* d_in, const int* in_sizes, int n_in,
                              void* d_out, int out_size, void* d_ws, size_t ws_size,
                              hipStream_t stream) {
  const float* x  = (const float*)d_in[0];
  const float* Wq = (const float*)d_in[1];
  const float* Wk = (const float*)d_in[2];
  const float* Wv = (const float*)d_in[3];
  const float* Wo = (const float*)d_in[4];
  float* out = (float*)d_out;

  char* p = (char*)d_ws;
  bf16* xb   = (bf16*)p; p += (size_t)8388608 * 2;    // x bf16 (4096x2048)
  bf16* wqkv = (bf16*)p; p += (size_t)12582912 * 2;   // [Wq;Wk;Wv] (6144x2048)
  bf16* wob  = (bf16*)p; p += (size_t)4194304 * 2;    // Wo bf16
  bf16* Qp   = (bf16*)p; p += (size_t)8388608 * 2;    // roped (b,h,n,128)
  bf16* Kp   = (bf16*)p; p += (size_t)8388608 * 2;    // roped (b,h,n,128)
  bf16* Vt   = (bf16*)p; p += (size_t)8388608 * 2;    // (b,h,128,n)
  bf16* Ob   = (bf16*)p; p += (size_t)8388608 * 2;    // attn out (b,n,h*128)
  float* ct  = (float*)p; p += (size_t)131072 * 4;
  float* st  = (float*)p; p += (size_t)131072 * 4;

  k_cvt<<<8192, 256, 0, stream>>>(x, xb, 2097152);
  k_cvt3<<<12288, 256, 0, stream>>>(Wq, Wk, Wv, wqkv);
  k_cvt<<<4096, 256, 0, stream>>>(Wo, wob, 1048576);
  k_rope_tab<<<512, 256, 0, stream>>>(ct, st);

  k_gemm_qkv<<<384, 512, 0, stream>>>(xb, wqkv, Qp, Kp, Vt, ct, st);

  k_attn<<<512, 256, 0, stream>>>(Qp, Kp, Vt, Ob);

  k_gemm_out<<<dim3(16, 32), 256, 0, stream>>>(Ob, wob, out);
}

// Round 6
// 276.343 us; speedup vs baseline: 1.0025x; 1.0025x over previous
//
#include <hip/hip_runtime.h>

// PolyAttention on MI355X (gfx950).
// cvt f32->bf16 -> fused QKV GEMM (256x128, BK=64, 3-buffer deep pipeline,
// counted vmcnt(6), swizzled LDS, rope fused, V transposed) -> causal poly(^4)
// attention -> output GEMM.  b=2, n=2048, d=2048, h=16, hd=128.

typedef __bf16 bf16;
typedef __bf16 bf16x8 __attribute__((ext_vector_type(8)));
typedef __bf16 bf16x4 __attribute__((ext_vector_type(4)));
typedef float f32x4 __attribute__((ext_vector_type(4)));

#define GLD(g, l)                                                   \
  __builtin_amdgcn_global_load_lds(                                 \
      (const __attribute__((address_space(1))) void*)(g),           \
      (__attribute__((address_space(3))) void*)(l), 16, 0, 0)

#define MFMA(a, b, c) __builtin_amdgcn_mfma_f32_16x16x32_bf16(a, b, c, 0, 0, 0)

// ---------- f32 -> bf16 conversion, 4 elems/thread ----------
__global__ __launch_bounds__(256) void k_cvt(const float* __restrict__ in,
                                             bf16* __restrict__ out, int n4) {
  int i = blockIdx.x * 256 + threadIdx.x;
  if (i >= n4) return;
  float4 v = reinterpret_cast<const float4*>(in)[i];
  bf16x4 o = {(bf16)v.x, (bf16)v.y, (bf16)v.z, (bf16)v.w};
  reinterpret_cast<bf16x4*>(out)[i] = o;
}

// ---------- 3x weight cvt into concatenated wqkv (6144 x 2048) ----------
__global__ __launch_bounds__(256) void k_cvt3(const float* __restrict__ a,
                                              const float* __restrict__ b,
                                              const float* __restrict__ c,
                                              bf16* __restrict__ out) {
  int i = blockIdx.x * 256 + threadIdx.x;
  const float* src = (i < 1048576) ? a : ((i < 2097152) ? b : c);
  int off = i & 1048575;
  float4 v = reinterpret_cast<const float4*>(src)[off];
  bf16x4 o = {(bf16)v.x, (bf16)v.y, (bf16)v.z, (bf16)v.w};
  reinterpret_cast<bf16x4*>(out)[i] = o;
}

// ---------- RoPE cos/sin table: (n=2048, half=64) ----------
__global__ __launch_bounds__(256) void k_rope_tab(float* __restrict__ ct,
                                                  float* __restrict__ st) {
  int i = blockIdx.x * 256 + threadIdx.x;
  if (i >= 2048 * 64) return;
  int pos = i >> 6, f = i & 63;
  float theta = exp2f(-(float)f * 0.20762050593046014f);  // 10000^(-f/64)
  float ang = (float)pos * theta;
  ct[i] = cosf(ang);
  st[i] = sinf(ang);
}

// ---------- fused QKV GEMM: 256x128 tile, BK=64, 3-buffer deep pipeline ----------
// 8 waves (2M x 4N), per-wave 128x32 (8x2 frags). LDS: 3 bufs x (A 32KB + B 16KB).
// Stage targets buf (k+2)%3 (dead since tile k-1: NO WAR). 6 GLD/tile (3 per
// phase); ONE gate vmcnt(6) per K-tile at P1-end: tile k+1 (staged @k-1, >=4
// phases of flight) proven landed; tile k+2's 6 loads stay airborne.
__global__ __launch_bounds__(512, 2) void k_gemm_qkv(
    const bf16* __restrict__ Am, const bf16* __restrict__ Bm,
    bf16* __restrict__ Qp, bf16* __restrict__ Kp, bf16* __restrict__ Vt,
    const float* __restrict__ ct, const float* __restrict__ st) {
  __shared__ __align__(16) char LDS[147456];  // 3 x 48KB
  const int tid = threadIdx.x, l = tid & 63, w = tid >> 6;
  const int lr = l & 15, g = l >> 4;
  const int wm = w >> 2, wn = w & 3;
  // grid 768 = 16M x 48N; XCD k owns 6 N-strips (B 3MB fits its L2)
  const int swz = (blockIdx.x & 7) * 96 + (blockIdx.x >> 3);
  const int tm = (swz & 15) * 256;
  const int tn = (swz >> 4) * 128;

  // stage source (inverse-swizzled): LDS-row srow holds global chunk (c^(srow&7))
  const int srow = tid >> 3;
  const int scol = ((tid & 7) ^ (srow & 7)) << 3;  // elements
  const bf16* Au0 = Am + (size_t)(tm + srow) * 2048 + scol;
  const bf16* Au1 = Am + (size_t)(tm + 64 + srow) * 2048 + scol;
  const bf16* Au2 = Am + (size_t)(tm + 128 + srow) * 2048 + scol;
  const bf16* Au3 = Am + (size_t)(tm + 192 + srow) * 2048 + scol;
  const bf16* Bu0 = Bm + (size_t)(tn + srow) * 2048 + scol;
  const bf16* Bu1 = Bm + (size_t)(tn + 64 + srow) * 2048 + scol;

  // ds_read offsets (bytes): chunk (ks*4+g) ^ (lr&7)
  const int x0 = ((0 + g) ^ (lr & 7)) << 4;
  const int x1 = ((4 + g) ^ (lr & 7)) << 4;
  const int abase = wm * 16384 + lr * 128;            // + fm*2048 + x
  const int bbase = 32768 + wn * 4096 + lr * 128;     // + nf*2048 + x

#define SU(dst, src, kc) GLD((src) + (kc), LDS + (dst) + tid * 16)
#define STAGE_TILE(bb, kc)                                        \
  {                                                               \
    SU((bb) + 0, Au0, kc); SU((bb) + 8192, Au1, kc);              \
    SU((bb) + 16384, Au2, kc); SU((bb) + 24576, Au3, kc);         \
    SU((bb) + 32768, Bu0, kc); SU((bb) + 40960, Bu1, kc);         \
  }

  f32x4 acc[8][2] = {};

  STAGE_TILE(0, 0);
  STAGE_TILE(49152, 64);
  asm volatile("s_waitcnt vmcnt(6)" ::: "memory");  // tile0 landed, tile1 flying
  __builtin_amdgcn_s_barrier();

  int cur = 0;
  for (int k = 0; k < 32; ++k) {
    const int nx = ((k + 2) % 3) * 49152;
    const int kc = (k + 2 < 32 ? k + 2 : 31) * 64;  // clamped dummy keeps counts uniform
    const char* base = LDS + cur;
    bf16x8 a[8], b0, b1;

    // ---- P0 (ks=0) ----
#pragma unroll
    for (int fm = 0; fm < 8; ++fm)
      a[fm] = *reinterpret_cast<const bf16x8*>(base + abase + fm * 2048 + x0);
    b0 = *reinterpret_cast<const bf16x8*>(base + bbase + x0);
    b1 = *reinterpret_cast<const bf16x8*>(base + bbase + 2048 + x0);
    SU(nx + 0, Au0, kc);
    SU(nx + 8192, Au1, kc);
    SU(nx + 16384, Au2, kc);
    __builtin_amdgcn_s_barrier();
    __builtin_amdgcn_s_setprio(1);
#pragma unroll
    for (int fm = 0; fm < 8; ++fm) {
      acc[fm][0] = MFMA(a[fm], b0, acc[fm][0]);
      acc[fm][1] = MFMA(a[fm], b1, acc[fm][1]);
    }
    __builtin_amdgcn_s_setprio(0);
    __builtin_amdgcn_s_barrier();

    // ---- P1 (ks=1) ----
#pragma unroll
    for (int fm = 0; fm < 8; ++fm)
      a[fm] = *reinterpret_cast<const bf16x8*>(base + abase + fm * 2048 + x1);
    b0 = *reinterpret_cast<const bf16x8*>(base + bbase + x1);
    b1 = *reinterpret_cast<const bf16x8*>(base + bbase + 2048 + x1);
    SU(nx + 24576, Au3, kc);
    SU(nx + 32768, Bu0, kc);
    SU(nx + 40960, Bu1, kc);
    __builtin_amdgcn_s_barrier();
    __builtin_amdgcn_s_setprio(1);
#pragma unroll
    for (int fm = 0; fm < 8; ++fm) {
      acc[fm][0] = MFMA(a[fm], b0, acc[fm][0]);
      acc[fm][1] = MFMA(a[fm], b1, acc[fm][1]);
    }
    __builtin_amdgcn_s_setprio(0);
    asm volatile("s_waitcnt vmcnt(6)" ::: "memory");  // tile k+1 landed
    __builtin_amdgcn_s_barrier();
    cur = (cur == 98304) ? 0 : cur + 49152;
  }
  asm volatile("s_waitcnt vmcnt(0)" ::: "memory");
  __builtin_amdgcn_s_barrier();  // LDS reused by epilogue

  // ---- epilogue ----
  if (tn < 4096) {
    // Q or K tile (one head): LDS exchange + rope + store (b,h,n,128)
    bf16* E = (bf16*)LDS;  // [256][136]
#pragma unroll
    for (int fm = 0; fm < 8; ++fm)
#pragma unroll
      for (int nf = 0; nf < 2; ++nf)
#pragma unroll
        for (int rr = 0; rr < 4; ++rr)
          E[(wm * 128 + fm * 16 + g * 4 + rr) * 136 + wn * 32 + nf * 16 + lr] =
              (bf16)acc[fm][nf][rr];
    __syncthreads();
    const int hh = (tn & 2047) >> 7;
    bf16* dst = (tn < 2048) ? Qp : Kp;
#pragma unroll
    for (int it = 0; it < 8; ++it) {
      int task = it * 512 + tid;  // 256 rows x 16 d4-groups
      int row = task >> 4, dg = (task & 15) << 2;
      int token = tm + row, nn = token & 2047, bb = token >> 11;
      f32x4 c4 = *reinterpret_cast<const f32x4*>(ct + nn * 64 + dg);
      f32x4 s4 = *reinterpret_cast<const f32x4*>(st + nn * 64 + dg);
      bf16x4 x1v = *reinterpret_cast<const bf16x4*>(E + row * 136 + dg);
      bf16x4 x2v = *reinterpret_cast<const bf16x4*>(E + row * 136 + 64 + dg);
      bf16x4 o1, o2;
#pragma unroll
      for (int j = 0; j < 4; ++j) {
        float a1 = (float)x1v[j], a2 = (float)x2v[j];
        o1[j] = (bf16)(a1 * c4[j] - a2 * s4[j]);
        o2[j] = (bf16)(a1 * s4[j] + a2 * c4[j]);
      }
      size_t rb = (((size_t)bb * 16 + hh) * 2048 + nn) * 128;
      *reinterpret_cast<bf16x4*>(dst + rb + dg) = o1;
      *reinterpret_cast<bf16x4*>(dst + rb + 64 + dg) = o2;
    }
  } else {
    // V: transposed store (b,h,128,n), 4 consecutive tokens per bf16x4
#pragma unroll
    for (int fm = 0; fm < 8; ++fm)
#pragma unroll
      for (int nf = 0; nf < 2; ++nf) {
        int row0 = tm + wm * 128 + fm * 16 + g * 4;
        int col = (tn - 4096) + wn * 32 + nf * 16 + lr;
        int bb = row0 >> 11, nn = row0 & 2047;
        int hh = col >> 7, dd = col & 127;
        bf16x4 o = {(bf16)acc[fm][nf][0], (bf16)acc[fm][nf][1],
                    (bf16)acc[fm][nf][2], (bf16)acc[fm][nf][3]};
        *reinterpret_cast<bf16x4*>(
            Vt + (((size_t)bb * 16 + hh) * 128 + dd) * 2048 + nn) = o;
      }
  }
}

// ---------- output GEMM: C(f32) = A * B^T, 4096x2048x2048 (round-4, kept) ----------
__global__ __launch_bounds__(256, 3) void k_gemm_out(const bf16* __restrict__ Am,
                                                     const bf16* __restrict__ Bm,
                                                     float* __restrict__ C) {
  __shared__ __align__(16) char LDS[49152];  // 3 x (8KB A + 8KB B)
  const int tid = threadIdx.x, w = tid >> 6, l = tid & 63;
  const int lr = l & 15, g = l >> 4;
  const int wr = w >> 1, wc = w & 1;
  const int tm = blockIdx.y * 128, tn = blockIdx.x * 128;

  const int rl = tid >> 2;
  const int scol = (((tid & 3) ^ (rl & 3) ^ ((rl >> 2) & 3)) << 3);
  const int xo = ((g ^ (lr & 3) ^ ((lr >> 2) & 3)) << 4);

#define STAGEO(buf, kt)                                                      \
  {                                                                          \
    _Pragma("unroll") for (int i = 0; i < 2; ++i)                            \
        GLD(Am + (size_t)(tm + i * 64 + rl) * 2048 + (kt) + scol,            \
            LDS + (buf) * 16384 + i * 4096 + tid * 16);                      \
    _Pragma("unroll") for (int i = 0; i < 2; ++i)                            \
        GLD(Bm + (size_t)(tn + i * 64 + rl) * 2048 + (kt) + scol,            \
            LDS + (buf) * 16384 + 8192 + i * 4096 + tid * 16);               \
  }

  f32x4 acc[4][4] = {};

  STAGEO(0, 0);
  STAGEO(1, 32);
  int cur = 0, st3 = 2;
  for (int t = 0; t < 63; ++t) {
    asm volatile("s_waitcnt vmcnt(4)" ::: "memory");
    __builtin_amdgcn_s_barrier();
    asm volatile("" ::: "memory");
    if (t < 62) STAGEO(st3, (t + 2) * 32);
    const char* pa = LDS + cur * 16384;
    const char* pb = pa + 8192;
    bf16x8 a[4], b[4];
#pragma unroll
    for (int fm = 0; fm < 4; ++fm)
      a[fm] = *reinterpret_cast<const bf16x8*>(pa + (wr * 64 + fm * 16 + lr) * 64 + xo);
#pragma unroll
    for (int nf = 0; nf < 4; ++nf)
      b[nf] = *reinterpret_cast<const bf16x8*>(pb + (wc * 64 + nf * 16 + lr) * 64 + xo);
    __builtin_amdgcn_s_setprio(1);
#pragma unroll
    for (int fm = 0; fm < 4; ++fm)
#pragma unroll
      for (int nf = 0; nf < 4; ++nf)
        acc[fm][nf] = MFMA(a[fm], b[nf], acc[fm][nf]);
    __builtin_amdgcn_s_setprio(0);
    cur = (cur == 2) ? 0 : cur + 1;
    st3 = (st3 == 2) ? 0 : st3 + 1;
  }
  {
    asm volatile("s_waitcnt vmcnt(0)" ::: "memory");
    __builtin_amdgcn_s_barrier();
    asm volatile("" ::: "memory");
    const char* pa = LDS + cur * 16384;
    const char* pb = pa + 8192;
    bf16x8 a[4], b[4];
#pragma unroll
    for (int fm = 0; fm < 4; ++fm)
      a[fm] = *reinterpret_cast<const bf16x8*>(pa + (wr * 64 + fm * 16 + lr) * 64 + xo);
#pragma unroll
    for (int nf = 0; nf < 4; ++nf)
      b[nf] = *reinterpret_cast<const bf16x8*>(pb + (wc * 64 + nf * 16 + lr) * 64 + xo);
#pragma unroll
    for (int fm = 0; fm < 4; ++fm)
#pragma unroll
      for (int nf = 0; nf < 4; ++nf)
        acc[fm][nf] = MFMA(a[fm], b[nf], acc[fm][nf]);
  }

#pragma unroll
  for (int fm = 0; fm < 4; ++fm)
#pragma unroll
    for (int nf = 0; nf < 4; ++nf)
#pragma unroll
      for (int rr = 0; rr < 4; ++rr) {
        int row = tm + wr * 64 + fm * 16 + g * 4 + rr;
        int col = tn + wc * 64 + nf * 16 + lr;
        C[(size_t)row * 2048 + col] = acc[fm][nf][rr];
      }
}

// ---------- causal poly^4 attention (unchanged) ----------
__global__ __launch_bounds__(256) void k_attn(const bf16* __restrict__ Q,
                                              const bf16* __restrict__ K,
                                              const bf16* __restrict__ Vt,
                                              bf16* __restrict__ O) {
  __shared__ __align__(16) bf16 Ks[128 * 128];
  __shared__ __align__(16) bf16 Vs[128 * 128];  // [hd][kv]
  __shared__ __align__(16) bf16 Ps[64 * 128];
  const int tid = threadIdx.x, w = tid >> 6, l = tid & 63;
  const int lr = l & 15, g = l >> 4;
  const int flat = blockIdx.x;
  const int pair = flat >> 5, bh = flat & 31;
  const size_t base = (size_t)bh * 2048 * 128;
  const int b_ = bh >> 4, h_ = bh & 15;

  for (int seg = 0; seg < 2; ++seg) {
    const int qt = seg ? (31 - pair) : pair;
    const int qbase = qt * 64;
    bf16x8 qf[4];
#pragma unroll
    for (int kc = 0; kc < 4; ++kc)
      qf[kc] = *reinterpret_cast<const bf16x8*>(
          Q + base + (size_t)(qbase + w * 16 + lr) * 128 + kc * 32 + g * 8);

    f32x4 on[8] = {};
    float dn[4] = {};
    const int nt = (qbase >> 7) + 1;

    for (int t = 0; t < nt; ++t) {
      const bf16* kg = K + base + (size_t)t * 128 * 128;
      const bf16* vg = Vt + base + t * 128;
#pragma unroll
      for (int r = 0; r < 8; ++r) {
        int e = r * 2048 + w * 512 + l * 8;
        int row = e >> 7, c = (e >> 3) & 15;
        int sc = ((c ^ (row & 7)) << 3);
        GLD(kg + (row << 7) + sc, Ks + r * 2048 + w * 512);
        GLD(vg + (size_t)row * 2048 + sc, Vs + r * 2048 + w * 512);
      }
      __syncthreads();

      f32x4 s[8] = {};
      __builtin_amdgcn_s_setprio(1);
#pragma unroll
      for (int kc = 0; kc < 4; ++kc)
#pragma unroll
        for (int ni = 0; ni < 8; ++ni) {
          bf16x8 kb = *reinterpret_cast<const bf16x8*>(
              Ks + ((ni * 16 + lr) << 7) + (((kc * 4 + g) ^ (lr & 7)) << 3));
          s[ni] = MFMA(qf[kc], kb, s[ni]);
        }
      __builtin_amdgcn_s_setprio(0);

      float part[4] = {};
#pragma unroll
      for (int ni = 0; ni < 8; ++ni)
#pragma unroll
        for (int r = 0; r < 4; ++r) {
          int lrow = g * 4 + r;
          int qrow = qbase + w * 16 + lrow;
          int col = t * 128 + ni * 16 + lr;
          float v = s[ni][r];
          v = (col <= qrow) ? v : 0.f;
          float v2 = v * v, v4 = v2 * v2;
          part[r] += v4;
          int chunk = ni * 2 + (lr >> 3);
          Ps[((w * 16 + lrow) << 7) + ((chunk ^ (lrow & 7)) << 3) + (lr & 7)] =
              (bf16)v4;
        }
#pragma unroll
      for (int m = 1; m < 16; m <<= 1)
#pragma unroll
        for (int r = 0; r < 4; ++r) part[r] += __shfl_xor(part[r], m, 64);
#pragma unroll
      for (int r = 0; r < 4; ++r) dn[r] += part[r];

      __builtin_amdgcn_s_setprio(1);
#pragma unroll
      for (int kc = 0; kc < 4; ++kc) {
        bf16x8 pa = *reinterpret_cast<const bf16x8*>(
            Ps + ((w * 16 + lr) << 7) + (((kc * 4 + g) ^ (lr & 7)) << 3));
#pragma unroll
        for (int ni = 0; ni < 8; ++ni) {
          bf16x8 vb = *reinterpret_cast<const bf16x8*>(
              Vs + ((ni * 16 + lr) << 7) + (((kc * 4 + g) ^ (lr & 7)) << 3));
          on[ni] = MFMA(pa, vb, on[ni]);
        }
      }
      __builtin_amdgcn_s_setprio(0);
      __syncthreads();
    }

#pragma unroll
    for (int r = 0; r < 4; ++r) {
      float inv = 1.0f / fmaxf(dn[r], 1e-6f);
      int row = qbase + w * 16 + g * 4 + r;
#pragma unroll
      for (int ni = 0; ni < 8; ++ni)
        O[((size_t)b_ * 2048 + row) * 2048 + h_ * 128 + ni * 16 + lr] =
            (bf16)(on[ni][r] * inv);
    }
  }
}

extern "C" void kernel_launch(void* const* d_in, const int* in_sizes, int n_in,
                              void* d_out, int out_size, void* d_ws, size_t ws_size,
                              hipStream_t stream) {
  const float* x  = (const float*)d_in[0];
  const float* Wq = (const float*)d_in[1];
  const float* Wk = (const float*)d_in[2];
  const float* Wv = (const float*)d_in[3];
  const float* Wo = (const float*)d_in[4];
  float* out = (float*)d_out;

  char* p = (char*)d_ws;
  bf16* xb   = (bf16*)p; p += (size_t)8388608 * 2;    // x bf16 (4096x2048)
  bf16* wqkv = (bf16*)p; p += (size_t)12582912 * 2;   // [Wq;Wk;Wv] (6144x2048)
  bf16* wob  = (bf16*)p; p += (size_t)4194304 * 2;    // Wo bf16
  bf16* Qp   = (bf16*)p; p += (size_t)8388608 * 2;    // roped (b,h,n,128)
  bf16* Kp   = (bf16*)p; p += (size_t)8388608 * 2;    // roped (b,h,n,128)
  bf16* Vt   = (bf16*)p; p += (size_t)8388608 * 2;    // (b,h,128,n)
  bf16* Ob   = (bf16*)p; p += (size_t)8388608 * 2;    // attn out (b,n,h*128)
  float* ct  = (float*)p; p += (size_t)131072 * 4;
  float* st  = (float*)p; p += (size_t)131072 * 4;

  k_cvt<<<8192, 256, 0, stream>>>(x, xb, 2097152);
  k_cvt3<<<12288, 256, 0, stream>>>(Wq, Wk, Wv, wqkv);
  k_cvt<<<4096, 256, 0, stream>>>(Wo, wob, 1048576);
  k_rope_tab<<<512, 256, 0, stream>>>(ct, st);

  k_gemm_qkv<<<768, 512, 0, stream>>>(xb, wqkv, Qp, Kp, Vt, ct, st);

  k_attn<<<512, 256, 0, stream>>>(Qp, Kp, Vt, Ob);

  k_gemm_out<<<dim3(16, 32), 256, 0, stream>>>(Ob, wob, out);
}

// Round 7
// 271.390 us; speedup vs baseline: 1.0208x; 1.0182x over previous
//
#include <hip/hip_runtime.h>

// PolyAttention on MI355X (gfx950).
// cvt f32->bf16 -> fused QKV GEMM (256x128, BK=32, triple-buffer LDS, counted
// vmcnt pipeline, rope fused in epilogue, V transposed) -> causal poly(^4)
// attention (MFMA ones-column denominator, diagonal-only mask) -> output GEMM.
// Shapes: b=2, n=2048, d=2048, h=16, hd=128.

typedef __bf16 bf16;
typedef __bf16 bf16x8 __attribute__((ext_vector_type(8)));
typedef __bf16 bf16x4 __attribute__((ext_vector_type(4)));
typedef float f32x4 __attribute__((ext_vector_type(4)));

#define GLD(g, l)                                                   \
  __builtin_amdgcn_global_load_lds(                                 \
      (const __attribute__((address_space(1))) void*)(g),           \
      (__attribute__((address_space(3))) void*)(l), 16, 0, 0)

#define MFMA(a, b, c) __builtin_amdgcn_mfma_f32_16x16x32_bf16(a, b, c, 0, 0, 0)

// ---------- f32 -> bf16 conversion, 4 elems/thread ----------
__global__ __launch_bounds__(256) void k_cvt(const float* __restrict__ in,
                                             bf16* __restrict__ out, int n4) {
  int i = blockIdx.x * 256 + threadIdx.x;
  if (i >= n4) return;
  float4 v = reinterpret_cast<const float4*>(in)[i];
  bf16x4 o = {(bf16)v.x, (bf16)v.y, (bf16)v.z, (bf16)v.w};
  reinterpret_cast<bf16x4*>(out)[i] = o;
}

// ---------- 3x weight cvt into concatenated wqkv (6144 x 2048) ----------
__global__ __launch_bounds__(256) void k_cvt3(const float* __restrict__ a,
                                              const float* __restrict__ b,
                                              const float* __restrict__ c,
                                              bf16* __restrict__ out) {
  int i = blockIdx.x * 256 + threadIdx.x;
  const float* src = (i < 1048576) ? a : ((i < 2097152) ? b : c);
  int off = i & 1048575;
  float4 v = reinterpret_cast<const float4*>(src)[off];
  bf16x4 o = {(bf16)v.x, (bf16)v.y, (bf16)v.z, (bf16)v.w};
  reinterpret_cast<bf16x4*>(out)[i] = o;
}

// ---------- RoPE cos/sin table: (n=2048, half=64) ----------
__global__ __launch_bounds__(256) void k_rope_tab(float* __restrict__ ct,
                                                  float* __restrict__ st) {
  int i = blockIdx.x * 256 + threadIdx.x;
  if (i >= 2048 * 64) return;
  int pos = i >> 6, f = i & 63;
  float theta = exp2f(-(float)f * 0.20762050593046014f);  // 10000^(-f/64)
  float ang = (float)pos * theta;
  ct[i] = cosf(ang);
  st[i] = sinf(ang);
}

// ---------- fused QKV GEMM + rope epilogue (round-4 version, kept) ----------
__global__ __launch_bounds__(256, 2) void k_gemm_qkv(
    const bf16* __restrict__ Am, const bf16* __restrict__ Bm,
    bf16* __restrict__ Qp, bf16* __restrict__ Kp, bf16* __restrict__ Vt,
    const float* __restrict__ ct, const float* __restrict__ st) {
  __shared__ __align__(16) char LDS[73728];  // 3 x (16KB A + 8KB B)
  const int tid = threadIdx.x, w = tid >> 6, l = tid & 63;
  const int lr = l & 15, g = l >> 4;
  const int wr = w >> 1, wc = w & 1;
  const int tm = blockIdx.y * 256, tn = blockIdx.x * 128;

  const int rl = tid >> 2;
  const int scol = (((tid & 3) ^ (rl & 3) ^ ((rl >> 2) & 3)) << 3);
  const int xo = ((g ^ (lr & 3) ^ ((lr >> 2) & 3)) << 4);

#define STAGEQ(buf, kt)                                                      \
  {                                                                          \
    _Pragma("unroll") for (int i = 0; i < 4; ++i)                            \
        GLD(Am + (size_t)(tm + i * 64 + rl) * 2048 + (kt) + scol,            \
            LDS + (buf) * 24576 + i * 4096 + tid * 16);                      \
    _Pragma("unroll") for (int i = 0; i < 2; ++i)                            \
        GLD(Bm + (size_t)(tn + i * 64 + rl) * 2048 + (kt) + scol,            \
            LDS + (buf) * 24576 + 16384 + i * 4096 + tid * 16);              \
  }

  f32x4 acc[8][4] = {};

  STAGEQ(0, 0);
  STAGEQ(1, 32);
  int cur = 0, st3 = 2;
  for (int t = 0; t < 63; ++t) {
    asm volatile("s_waitcnt vmcnt(6)" ::: "memory");
    __builtin_amdgcn_s_barrier();
    asm volatile("" ::: "memory");
    if (t < 62) STAGEQ(st3, (t + 2) * 32);
    const char* pa = LDS + cur * 24576;
    const char* pb = pa + 16384;
    bf16x8 a[8], b[4];
#pragma unroll
    for (int fm = 0; fm < 8; ++fm)
      a[fm] = *reinterpret_cast<const bf16x8*>(pa + (wr * 128 + fm * 16 + lr) * 64 + xo);
#pragma unroll
    for (int nf = 0; nf < 4; ++nf)
      b[nf] = *reinterpret_cast<const bf16x8*>(pb + (wc * 64 + nf * 16 + lr) * 64 + xo);
    __builtin_amdgcn_s_setprio(1);
#pragma unroll
    for (int fm = 0; fm < 8; ++fm)
#pragma unroll
      for (int nf = 0; nf < 4; ++nf)
        acc[fm][nf] = MFMA(a[fm], b[nf], acc[fm][nf]);
    __builtin_amdgcn_s_setprio(0);
    cur = (cur == 2) ? 0 : cur + 1;
    st3 = (st3 == 2) ? 0 : st3 + 1;
  }
  {  // peeled last tile
    asm volatile("s_waitcnt vmcnt(0)" ::: "memory");
    __builtin_amdgcn_s_barrier();
    asm volatile("" ::: "memory");
    const char* pa = LDS + cur * 24576;
    const char* pb = pa + 16384;
    bf16x8 a[8], b[4];
#pragma unroll
    for (int fm = 0; fm < 8; ++fm)
      a[fm] = *reinterpret_cast<const bf16x8*>(pa + (wr * 128 + fm * 16 + lr) * 64 + xo);
#pragma unroll
    for (int nf = 0; nf < 4; ++nf)
      b[nf] = *reinterpret_cast<const bf16x8*>(pb + (wc * 64 + nf * 16 + lr) * 64 + xo);
#pragma unroll
    for (int fm = 0; fm < 8; ++fm)
#pragma unroll
      for (int nf = 0; nf < 4; ++nf)
        acc[fm][nf] = MFMA(a[fm], b[nf], acc[fm][nf]);
  }

  if (tn < 4096) {
    __syncthreads();
    bf16* E = (bf16*)LDS;  // [256][136]
#pragma unroll
    for (int fm = 0; fm < 8; ++fm)
#pragma unroll
      for (int nf = 0; nf < 4; ++nf)
#pragma unroll
        for (int rr = 0; rr < 4; ++rr)
          E[(wr * 128 + fm * 16 + g * 4 + rr) * 136 + wc * 64 + nf * 16 + lr] =
              (bf16)acc[fm][nf][rr];
    __syncthreads();
    const int hh = (tn & 2047) >> 7;
    bf16* dst = (tn < 2048) ? Qp : Kp;
#pragma unroll
    for (int i = 0; i < 16; ++i) {
      int task = i * 256 + tid;
      int row = task >> 4, dg = (task & 15) << 2;
      int token = tm + row, nn = token & 2047, bb = token >> 11;
      f32x4 c4 = *reinterpret_cast<const f32x4*>(ct + nn * 64 + dg);
      f32x4 s4 = *reinterpret_cast<const f32x4*>(st + nn * 64 + dg);
      bf16x4 x1 = *reinterpret_cast<const bf16x4*>(E + row * 136 + dg);
      bf16x4 x2 = *reinterpret_cast<const bf16x4*>(E + row * 136 + 64 + dg);
      bf16x4 o1, o2;
#pragma unroll
      for (int j = 0; j < 4; ++j) {
        float a1 = (float)x1[j], a2 = (float)x2[j];
        o1[j] = (bf16)(a1 * c4[j] - a2 * s4[j]);
        o2[j] = (bf16)(a1 * s4[j] + a2 * c4[j]);
      }
      size_t rb = (((size_t)bb * 16 + hh) * 2048 + nn) * 128;
      *reinterpret_cast<bf16x4*>(dst + rb + dg) = o1;
      *reinterpret_cast<bf16x4*>(dst + rb + 64 + dg) = o2;
    }
  } else {
#pragma unroll
    for (int fm = 0; fm < 8; ++fm)
#pragma unroll
      for (int nf = 0; nf < 4; ++nf) {
        int row0 = tm + wr * 128 + fm * 16 + g * 4;
        int col = (tn - 4096) + wc * 64 + nf * 16 + lr;
        int bb = row0 >> 11, nn = row0 & 2047;
        int hh = col >> 7, dd = col & 127;
        bf16x4 o = {(bf16)acc[fm][nf][0], (bf16)acc[fm][nf][1],
                    (bf16)acc[fm][nf][2], (bf16)acc[fm][nf][3]};
        *reinterpret_cast<bf16x4*>(
            Vt + (((size_t)bb * 16 + hh) * 128 + dd) * 2048 + nn) = o;
      }
  }
}

// ---------- output GEMM: C(f32) = A * B^T, 4096x2048x2048 (round-4, kept) ----------
__global__ __launch_bounds__(256, 3) void k_gemm_out(const bf16* __restrict__ Am,
                                                     const bf16* __restrict__ Bm,
                                                     float* __restrict__ C) {
  __shared__ __align__(16) char LDS[49152];
  const int tid = threadIdx.x, w = tid >> 6, l = tid & 63;
  const int lr = l & 15, g = l >> 4;
  const int wr = w >> 1, wc = w & 1;
  const int tm = blockIdx.y * 128, tn = blockIdx.x * 128;

  const int rl = tid >> 2;
  const int scol = (((tid & 3) ^ (rl & 3) ^ ((rl >> 2) & 3)) << 3);
  const int xo = ((g ^ (lr & 3) ^ ((lr >> 2) & 3)) << 4);

#define STAGEO(buf, kt)                                                      \
  {                                                                          \
    _Pragma("unroll") for (int i = 0; i < 2; ++i)                            \
        GLD(Am + (size_t)(tm + i * 64 + rl) * 2048 + (kt) + scol,            \
            LDS + (buf) * 16384 + i * 4096 + tid * 16);                      \
    _Pragma("unroll") for (int i = 0; i < 2; ++i)                            \
        GLD(Bm + (size_t)(tn + i * 64 + rl) * 2048 + (kt) + scol,            \
            LDS + (buf) * 16384 + 8192 + i * 4096 + tid * 16);               \
  }

  f32x4 acc[4][4] = {};

  STAGEO(0, 0);
  STAGEO(1, 32);
  int cur = 0, st3 = 2;
  for (int t = 0; t < 63; ++t) {
    asm volatile("s_waitcnt vmcnt(4)" ::: "memory");
    __builtin_amdgcn_s_barrier();
    asm volatile("" ::: "memory");
    if (t < 62) STAGEO(st3, (t + 2) * 32);
    const char* pa = LDS + cur * 16384;
    const char* pb = pa + 8192;
    bf16x8 a[4], b[4];
#pragma unroll
    for (int fm = 0; fm < 4; ++fm)
      a[fm] = *reinterpret_cast<const bf16x8*>(pa + (wr * 64 + fm * 16 + lr) * 64 + xo);
#pragma unroll
    for (int nf = 0; nf < 4; ++nf)
      b[nf] = *reinterpret_cast<const bf16x8*>(pb + (wc * 64 + nf * 16 + lr) * 64 + xo);
    __builtin_amdgcn_s_setprio(1);
#pragma unroll
    for (int fm = 0; fm < 4; ++fm)
#pragma unroll
      for (int nf = 0; nf < 4; ++nf)
        acc[fm][nf] = MFMA(a[fm], b[nf], acc[fm][nf]);
    __builtin_amdgcn_s_setprio(0);
    cur = (cur == 2) ? 0 : cur + 1;
    st3 = (st3 == 2) ? 0 : st3 + 1;
  }
  {
    asm volatile("s_waitcnt vmcnt(0)" ::: "memory");
    __builtin_amdgcn_s_barrier();
    asm volatile("" ::: "memory");
    const char* pa = LDS + cur * 16384;
    const char* pb = pa + 8192;
    bf16x8 a[4], b[4];
#pragma unroll
    for (int fm = 0; fm < 4; ++fm)
      a[fm] = *reinterpret_cast<const bf16x8*>(pa + (wr * 64 + fm * 16 + lr) * 64 + xo);
#pragma unroll
    for (int nf = 0; nf < 4; ++nf)
      b[nf] = *reinterpret_cast<const bf16x8*>(pb + (wc * 64 + nf * 16 + lr) * 64 + xo);
#pragma unroll
    for (int fm = 0; fm < 4; ++fm)
#pragma unroll
      for (int nf = 0; nf < 4; ++nf)
        acc[fm][nf] = MFMA(a[fm], b[nf], acc[fm][nf]);
  }

#pragma unroll
  for (int fm = 0; fm < 4; ++fm)
#pragma unroll
    for (int nf = 0; nf < 4; ++nf)
#pragma unroll
      for (int rr = 0; rr < 4; ++rr) {
        int row = tm + wr * 64 + fm * 16 + g * 4 + rr;
        int col = tn + wc * 64 + nf * 16 + lr;
        C[(size_t)row * 2048 + col] = acc[fm][nf][rr];
      }
}

// ---------- causal poly^4 attention ----------
// Denominator via MFMA ones-column (dn4 += pa @ vones): kills the per-tile
// 16x shfl reduce. Causal mask applied only on the diagonal tile (others are
// provably unmasked). dn broadcast once at epilogue via one shfl per row.
__global__ __launch_bounds__(256) void k_attn(const bf16* __restrict__ Q,
                                              const bf16* __restrict__ K,
                                              const bf16* __restrict__ Vt,
                                              bf16* __restrict__ O) {
  __shared__ __align__(16) bf16 Ks[128 * 128];
  __shared__ __align__(16) bf16 Vs[128 * 128];  // [hd][kv]
  __shared__ __align__(16) bf16 Ps[64 * 128];
  const int tid = threadIdx.x, w = tid >> 6, l = tid & 63;
  const int lr = l & 15, g = l >> 4;
  const int flat = blockIdx.x;
  const int pair = flat >> 5, bh = flat & 31;
  const size_t base = (size_t)bh * 2048 * 128;
  const int b_ = bh >> 4, h_ = bh & 15;

  // ones B-fragment: output col 0 = row-sum of A (the denominator)
  bf16x8 vones = {};
  if (lr == 0) {
#pragma unroll
    for (int j = 0; j < 8; ++j) vones[j] = (bf16)1.0f;
  }

  for (int seg = 0; seg < 2; ++seg) {
    const int qt = seg ? (31 - pair) : pair;
    const int qbase = qt * 64;
    bf16x8 qf[4];
#pragma unroll
    for (int kc = 0; kc < 4; ++kc)
      qf[kc] = *reinterpret_cast<const bf16x8*>(
          Q + base + (size_t)(qbase + w * 16 + lr) * 128 + kc * 32 + g * 8);

    f32x4 on[8] = {};
    f32x4 dn4 = {0.f, 0.f, 0.f, 0.f};
    const int nt = (qbase >> 7) + 1;

    for (int t = 0; t < nt; ++t) {
      const bf16* kg = K + base + (size_t)t * 128 * 128;
      const bf16* vg = Vt + base + t * 128;
#pragma unroll
      for (int r = 0; r < 8; ++r) {
        int e = r * 2048 + w * 512 + l * 8;
        int row = e >> 7, c = (e >> 3) & 15;
        int sc = ((c ^ (row & 7)) << 3);
        GLD(kg + (row << 7) + sc, Ks + r * 2048 + w * 512);
        GLD(vg + (size_t)row * 2048 + sc, Vs + r * 2048 + w * 512);
      }
      __syncthreads();

      // S = Q K^T
      f32x4 s[8] = {};
      __builtin_amdgcn_s_setprio(1);
#pragma unroll
      for (int kc = 0; kc < 4; ++kc)
#pragma unroll
        for (int ni = 0; ni < 8; ++ni) {
          bf16x8 kb = *reinterpret_cast<const bf16x8*>(
              Ks + ((ni * 16 + lr) << 7) + (((kc * 4 + g) ^ (lr & 7)) << 3));
          s[ni] = MFMA(qf[kc], kb, s[ni]);
        }
      __builtin_amdgcn_s_setprio(0);

      // ^4 (+mask only on diagonal tile), swizzled Ps writes (own-wave rows)
      const bool diag = (t == nt - 1);
#pragma unroll
      for (int ni = 0; ni < 8; ++ni)
#pragma unroll
        for (int r = 0; r < 4; ++r) {
          int lrow = g * 4 + r;
          float v = s[ni][r];
          if (diag) {
            int qrow = qbase + w * 16 + lrow;
            int col = t * 128 + ni * 16 + lr;
            v = (col <= qrow) ? v : 0.f;
          }
          float v2 = v * v, v4 = v2 * v2;
          int chunk = ni * 2 + (lr >> 3);
          Ps[((w * 16 + lrow) << 7) + ((chunk ^ (lrow & 7)) << 3) + (lr & 7)] =
              (bf16)v4;
        }

      // O += P @ V ; dn4 += P @ ones
      __builtin_amdgcn_s_setprio(1);
#pragma unroll
      for (int kc = 0; kc < 4; ++kc) {
        bf16x8 pa = *reinterpret_cast<const bf16x8*>(
            Ps + ((w * 16 + lr) << 7) + (((kc * 4 + g) ^ (lr & 7)) << 3));
        dn4 = MFMA(pa, vones, dn4);
#pragma unroll
        for (int ni = 0; ni < 8; ++ni) {
          bf16x8 vb = *reinterpret_cast<const bf16x8*>(
              Vs + ((ni * 16 + lr) << 7) + (((kc * 4 + g) ^ (lr & 7)) << 3));
          on[ni] = MFMA(pa, vb, on[ni]);
        }
      }
      __builtin_amdgcn_s_setprio(0);
      __syncthreads();
    }

    // epilogue: broadcast denom from lane (g*16), divide, store
#pragma unroll
    for (int r = 0; r < 4; ++r) {
      float d = __shfl(dn4[r], l & 48);  // lane with lr==0 in this g-group
      float inv = 1.0f / fmaxf(d, 1e-6f);
      int row = qbase + w * 16 + g * 4 + r;
#pragma unroll
      for (int ni = 0; ni < 8; ++ni)
        O[((size_t)b_ * 2048 + row) * 2048 + h_ * 128 + ni * 16 + lr] =
            (bf16)(on[ni][r] * inv);
    }
  }
}

extern "C" void kernel_launch(void* const* d_in, const int* in_sizes, int n_in,
                              void* d_out, int out_size, void* d_ws, size_t ws_size,
                              hipStream_t stream) {
  const float* x  = (const float*)d_in[0];
  const float* Wq = (const float*)d_in[1];
  const float* Wk = (const float*)d_in[2];
  const float* Wv = (const float*)d_in[3];
  const float* Wo = (const float*)d_in[4];
  float* out = (float*)d_out;

  char* p = (char*)d_ws;
  bf16* xb   = (bf16*)p; p += (size_t)8388608 * 2;    // x bf16 (4096x2048)
  bf16* wqkv = (bf16*)p; p += (size_t)12582912 * 2;   // [Wq;Wk;Wv] (6144x2048)
  bf16* wob  = (bf16*)p; p += (size_t)4194304 * 2;    // Wo bf16
  bf16* Qp   = (bf16*)p; p += (size_t)8388608 * 2;    // roped (b,h,n,128)
  bf16* Kp   = (bf16*)p; p += (size_t)8388608 * 2;    // roped (b,h,n,128)
  bf16* Vt   = (bf16*)p; p += (size_t)8388608 * 2;    // (b,h,128,n)
  bf16* Ob   = (bf16*)p; p += (size_t)8388608 * 2;    // attn out (b,n,h*128)
  float* ct  = (float*)p; p += (size_t)131072 * 4;
  float* st  = (float*)p; p += (size_t)131072 * 4;

  k_cvt<<<8192, 256, 0, stream>>>(x, xb, 2097152);
  k_cvt3<<<12288, 256, 0, stream>>>(Wq, Wk, Wv, wqkv);
  k_cvt<<<4096, 256, 0, stream>>>(Wo, wob, 1048576);
  k_rope_tab<<<512, 256, 0, stream>>>(ct, st);

  k_gemm_qkv<<<dim3(48, 16), 256, 0, stream>>>(xb, wqkv, Qp, Kp, Vt, ct, st);

  k_attn<<<512, 256, 0, stream>>>(Qp, Kp, Vt, Ob);

  k_gemm_out<<<dim3(16, 32), 256, 0, stream>>>(Ob, wob, out);
}